// Round 16
// baseline (446.196 us; speedup 1.0000x reference)
//
#include <hip/hip_runtime.h>

#define HD  128   // hidden dim
#define TM  32    // node rows per block in the GIN layer kernel
#define SYB 136   // bf16 LDS stride

typedef __attribute__((ext_vector_type(8))) short    short8;
typedef __attribute__((ext_vector_type(8))) _Float16 half8;
typedef __attribute__((ext_vector_type(4))) float    float4v;

// split fp32 -> bf16 hi + bf16 lo (RNE both), v == hi + lo to ~2^-17 rel
__device__ __forceinline__ void split_bf(float v, short& hi, short& lo) {
    unsigned bv = __float_as_uint(v);
    unsigned hb = (bv + 0x7FFFu + ((bv >> 16) & 1u)) & 0xFFFF0000u;
    hi = (short)(hb >> 16);
    float r = v - __uint_as_float(hb);
    unsigned rv = __float_as_uint(r);
    lo = (short)((rv + 0x7FFFu + ((rv >> 16) & 1u)) >> 16);
}

// ------------------------------------------------------------- CSR build ----
__global__ void k_degree(const int* __restrict__ dst, int* __restrict__ deg, int e)
{
    int i = blockIdx.x * 256 + threadIdx.x;
    if (i < e) atomicAdd(&deg[dst[i]], 1);
}

__global__ void k_scan1(const int* __restrict__ deg, int* __restrict__ rp,
                        int* __restrict__ bsum, int n)
{
    __shared__ int s[1024];
    int t = threadIdx.x;
    int i = blockIdx.x * 1024 + t;
    int v = (i < n) ? deg[i] : 0;
    s[t] = v; __syncthreads();
    for (int off = 1; off < 1024; off <<= 1) {
        int tmp = (t >= off) ? s[t - off] : 0;
        __syncthreads();
        s[t] += tmp;
        __syncthreads();
    }
    if (i < n) rp[i] = s[t] - v;
    if (t == 1023) bsum[blockIdx.x] = s[1023];
}

__global__ void k_scan2(int* __restrict__ bsum, int nb)
{
    __shared__ int s[128];
    int t = threadIdx.x;
    int v = (t < nb) ? bsum[t] : 0;
    s[t] = v; __syncthreads();
    for (int off = 1; off < 128; off <<= 1) {
        int tmp = (t >= off) ? s[t - off] : 0;
        __syncthreads();
        s[t] += tmp;
        __syncthreads();
    }
    if (t < nb) bsum[t] = s[t] - v;
}

__global__ void k_scan3(int* __restrict__ rp, const int* __restrict__ bsum, int n, int e)
{
    int i = blockIdx.x * 1024 + threadIdx.x;
    if (i < n) rp[i] += bsum[blockIdx.x];
    if (i == 0) rp[n] = e;
}

__global__ void k_fill(const int* __restrict__ src, const int* __restrict__ dst,
                       const int* __restrict__ rp, int* __restrict__ fill,
                       int* __restrict__ ci, int e)
{
    int i = blockIdx.x * 256 + threadIdx.x;
    if (i < e) {
        int d = dst[i];
        int p = atomicAdd(&fill[d], 1);
        ci[rp[d] + p] = src[i];
    }
}

// --------------------------------------------- weight split into B-frags ----
// frag idx f = ((ct*4 + kb)*64 + lane)*8 + j holds
// W[kb*32 + (lane>>4)*8 + j][ct*16 + (lane&15)]  (B-operand of 16x16x32)
__global__ void k_wsplit(const float* __restrict__ W1, const float* __restrict__ W2,
                         short* __restrict__ wh, short* __restrict__ wl, int total)
{
    int g = blockIdx.x * 256 + threadIdx.x;
    if (g >= total) return;
    int f  = g & 16383;
    int m  = (g >> 14) & 1;
    int l  = g >> 15;
    int j    = f & 7;
    int lane = (f >> 3) & 63;
    int kb   = (f >> 9) & 3;
    int ct   = f >> 11;
    int k  = kb * 32 + (lane >> 4) * 8 + j;
    int nn = ct * 16 + (lane & 15);
    const float* W = m ? W2 : W1;
    float v = W[(size_t)l * 16384 + k * 128 + nn];
    short h, lo; split_bf(v, h, lo);
    wh[g] = h; wl[g] = lo;
}

// ---------------------------------------- shared MLP body (GEMM1+GEMM2) ----
__device__ __forceinline__ void mlp_body(
    short* sAh, short* sAl, _Float16* __restrict__ xout,
    const short* __restrict__ w1h, const short* __restrict__ w1l,
    const short* __restrict__ w2h, const short* __restrict__ w2l,
    const float* __restrict__ b1, const float* __restrict__ b2,
    int row0, int n, int wv, int lane, int quad, int lrow)
{
    // B1 hi frags + bias (latency overlaps barrier + LDS reads)
    short8 Bh[2][4];
    {
        const short8* h8 = (const short8*)w1h;
#pragma unroll
        for (int c = 0; c < 2; ++c)
#pragma unroll
            for (int kb = 0; kb < 4; ++kb)
                Bh[c][kb] = h8[((2 * wv + c) * 4 + kb) * 64 + lane];
    }
    float bb0 = b1[(2 * wv + 0) * 16 + lrow];
    float bb1 = b1[(2 * wv + 1) * 16 + lrow];
    __syncthreads();

    // ---- GEMM1: H = relu(Y @ W1 + b1)
    float4v acc1[2][2];
#pragma unroll
    for (int rt = 0; rt < 2; ++rt) {
        acc1[rt][0] = (float4v){bb0, bb0, bb0, bb0};
        acc1[rt][1] = (float4v){bb1, bb1, bb1, bb1};
    }
    {
        const short8* l8 = (const short8*)w1l;
#pragma unroll
        for (int kb = 0; kb < 4; ++kb) {
            short8 Ah[2], Al[2];
#pragma unroll
            for (int rt = 0; rt < 2; ++rt) {
                int off = (rt * 16 + lrow) * SYB + kb * 32 + quad * 8;
                Ah[rt] = *(const short8*)&sAh[off];
                Al[rt] = *(const short8*)&sAl[off];
            }
            short8 Bl0 = l8[((2 * wv + 0) * 4 + kb) * 64 + lane];
            short8 Bl1 = l8[((2 * wv + 1) * 4 + kb) * 64 + lane];
#pragma unroll
            for (int rt = 0; rt < 2; ++rt) {
                acc1[rt][0] = __builtin_amdgcn_mfma_f32_16x16x32_bf16(Ah[rt], Bh[0][kb], acc1[rt][0], 0, 0, 0);
                acc1[rt][0] = __builtin_amdgcn_mfma_f32_16x16x32_bf16(Al[rt], Bh[0][kb], acc1[rt][0], 0, 0, 0);
                acc1[rt][0] = __builtin_amdgcn_mfma_f32_16x16x32_bf16(Ah[rt], Bl0,       acc1[rt][0], 0, 0, 0);
                acc1[rt][1] = __builtin_amdgcn_mfma_f32_16x16x32_bf16(Ah[rt], Bh[1][kb], acc1[rt][1], 0, 0, 0);
                acc1[rt][1] = __builtin_amdgcn_mfma_f32_16x16x32_bf16(Al[rt], Bh[1][kb], acc1[rt][1], 0, 0, 0);
                acc1[rt][1] = __builtin_amdgcn_mfma_f32_16x16x32_bf16(Ah[rt], Bl1,       acc1[rt][1], 0, 0, 0);
            }
        }
    }

    // B2 hi frags + bias (issue before barrier, overlap it)
    short8 Bh2[2][4];
    {
        const short8* h8 = (const short8*)w2h;
#pragma unroll
        for (int c = 0; c < 2; ++c)
#pragma unroll
            for (int kb = 0; kb < 4; ++kb)
                Bh2[c][kb] = h8[((2 * wv + c) * 4 + kb) * 64 + lane];
    }
    float cb0 = b2[(2 * wv + 0) * 16 + lrow];
    float cb1 = b2[(2 * wv + 1) * 16 + lrow];

    __syncthreads();   // all waves done reading Y from LDS

    // H (relu) -> split into sAh/sAl (overwrite Y)
#pragma unroll
    for (int rt = 0; rt < 2; ++rt)
#pragma unroll
        for (int c = 0; c < 2; ++c) {
            int col = (2 * wv + c) * 16 + lrow;
#pragma unroll
            for (int r = 0; r < 4; ++r) {
                int row = rt * 16 + quad * 4 + r;
                float v = fmaxf(acc1[rt][c][r], 0.f);
                short h, l; split_bf(v, h, l);
                sAh[row * SYB + col] = h;
                sAl[row * SYB + col] = l;
            }
        }
    __syncthreads();

    // ---- GEMM2: X' = relu(H @ W2 + b2)
    float4v acc2[2][2];
#pragma unroll
    for (int rt = 0; rt < 2; ++rt) {
        acc2[rt][0] = (float4v){cb0, cb0, cb0, cb0};
        acc2[rt][1] = (float4v){cb1, cb1, cb1, cb1};
    }
    {
        const short8* l8 = (const short8*)w2l;
#pragma unroll
        for (int kb = 0; kb < 4; ++kb) {
            short8 Ah[2], Al[2];
#pragma unroll
            for (int rt = 0; rt < 2; ++rt) {
                int off = (rt * 16 + lrow) * SYB + kb * 32 + quad * 8;
                Ah[rt] = *(const short8*)&sAh[off];
                Al[rt] = *(const short8*)&sAl[off];
            }
            short8 Bl0 = l8[((2 * wv + 0) * 4 + kb) * 64 + lane];
            short8 Bl1 = l8[((2 * wv + 1) * 4 + kb) * 64 + lane];
#pragma unroll
            for (int rt = 0; rt < 2; ++rt) {
                acc2[rt][0] = __builtin_amdgcn_mfma_f32_16x16x32_bf16(Ah[rt], Bh2[0][kb], acc2[rt][0], 0, 0, 0);
                acc2[rt][0] = __builtin_amdgcn_mfma_f32_16x16x32_bf16(Al[rt], Bh2[0][kb], acc2[rt][0], 0, 0, 0);
                acc2[rt][0] = __builtin_amdgcn_mfma_f32_16x16x32_bf16(Ah[rt], Bl0,        acc2[rt][0], 0, 0, 0);
                acc2[rt][1] = __builtin_amdgcn_mfma_f32_16x16x32_bf16(Ah[rt], Bh2[1][kb], acc2[rt][1], 0, 0, 0);
                acc2[rt][1] = __builtin_amdgcn_mfma_f32_16x16x32_bf16(Al[rt], Bh2[1][kb], acc2[rt][1], 0, 0, 0);
                acc2[rt][1] = __builtin_amdgcn_mfma_f32_16x16x32_bf16(Ah[rt], Bl1,        acc2[rt][1], 0, 0, 0);
            }
        }
    }

    // epilogue: relu + store fp16
#pragma unroll
    for (int rt = 0; rt < 2; ++rt)
#pragma unroll
        for (int c = 0; c < 2; ++c) {
            int col = (2 * wv + c) * 16 + lrow;
#pragma unroll
            for (int r = 0; r < 4; ++r) {
                int node = row0 + rt * 16 + quad * 4 + r;
                if (node < n)
                    xout[(size_t)node * HD + col] = (_Float16)fmaxf(acc2[rt][c][r], 0.f);
            }
        }
}

// --------------------------------- layer 0: embed fused into aggregation ----
__global__ __launch_bounds__(256, 4)
void k_gin0(const int* __restrict__ tok, const float* __restrict__ emb,
            _Float16* __restrict__ xout,
            const int* __restrict__ rp, const int* __restrict__ ci,
            const short* __restrict__ w1h, const short* __restrict__ w1l,
            const short* __restrict__ w2h, const short* __restrict__ w2l,
            const float* __restrict__ b1, const float* __restrict__ b2,
            int n)
{
    __shared__ short sAh[TM * SYB];
    __shared__ short sAl[TM * SYB];

    const int tx   = threadIdx.x;
    const int row0 = blockIdx.x * TM;
    const int wv   = tx >> 6, lane = tx & 63;
    const int quad = lane >> 4, lrow = lane & 15;

    // ---- aggregation: Y[row] = emb[tok[row]] + sum_j emb[tok[ci[j]]]
    // emb table = 64 KB (L1/L2-hot); per-edge global traffic = 4 B token
    {
        const int rl = tx >> 3, part = tx & 7;
        int node = row0 + rl;
        if (node >= n) node = n - 1;
        const float4* er = (const float4*)emb + ((size_t)tok[node] << 5) + part * 4;
        float4 s0 = er[0], s1 = er[1], s2 = er[2], s3 = er[3];
        float self_[2][8] = {{s0.x, s0.y, s0.z, s0.w, s1.x, s1.y, s1.z, s1.w},
                             {s2.x, s2.y, s2.z, s2.w, s3.x, s3.y, s3.z, s3.w}};
        float acc[2][8];
#pragma unroll
        for (int k = 0; k < 8; ++k) { acc[0][k] = self_[0][k]; acc[1][k] = self_[1][k]; }

        const int e0 = rp[node], e1 = rp[node + 1];
        for (int eb = e0; eb < e1; eb += 8) {
            int idx = eb + part;
            int c = (idx < e1) ? ci[idx] : node;
#pragma unroll
            for (int j = 0; j < 8; ++j) {
                int cj = __shfl(c, j, 8);
                const float4* ej = (const float4*)emb + ((size_t)tok[cj] << 5) + part * 4;
                float4 v0 = ej[0], v1 = ej[1], v2 = ej[2], v3 = ej[3];
                acc[0][0] += v0.x; acc[0][1] += v0.y; acc[0][2] += v0.z; acc[0][3] += v0.w;
                acc[0][4] += v1.x; acc[0][5] += v1.y; acc[0][6] += v1.z; acc[0][7] += v1.w;
                acc[1][0] += v2.x; acc[1][1] += v2.y; acc[1][2] += v2.z; acc[1][3] += v2.w;
                acc[1][4] += v3.x; acc[1][5] += v3.y; acc[1][6] += v3.z; acc[1][7] += v3.w;
            }
        }
        int deg = e1 - e0;
        if (deg) {
            float fx = (float)(((deg + 7) & ~7) - deg);
#pragma unroll
            for (int k = 0; k < 8; ++k) {
                acc[0][k] -= fx * self_[0][k];
                acc[1][k] -= fx * self_[1][k];
            }
        }
#pragma unroll
        for (int q = 0; q < 2; ++q) {
            short8 h8s, l8s;
#pragma unroll
            for (int k = 0; k < 8; ++k) { short h, l; split_bf(acc[q][k], h, l); h8s[k] = h; l8s[k] = l; }
            int off = rl * SYB + part * 16 + q * 8;
            *(short8*)&sAh[off] = h8s;
            *(short8*)&sAl[off] = l8s;
        }
    }

    mlp_body(sAh, sAl, xout, w1h, w1l, w2h, w2l, b1, b2, row0, n, wv, lane, quad, lrow);
}

// ------------------------------------------------- layers 1..L-1: fp16 x ----
__global__ __launch_bounds__(256, 4)
void k_gin(const _Float16* __restrict__ xin, _Float16* __restrict__ xout,
           const int* __restrict__ rp, const int* __restrict__ ci,
           const short* __restrict__ w1h, const short* __restrict__ w1l,
           const short* __restrict__ w2h, const short* __restrict__ w2l,
           const float* __restrict__ b1, const float* __restrict__ b2,
           int n)
{
    __shared__ short sAh[TM * SYB];
    __shared__ short sAl[TM * SYB];

    const int tx   = threadIdx.x;
    const int row0 = blockIdx.x * TM;
    const int wv   = tx >> 6, lane = tx & 63;
    const int quad = lane >> 4, lrow = lane & 15;

    // ---- aggregation: Y[row] = x[row] + sum_j x[j]
    // 8 lanes/row; shfl-broadcast 8-edge chunks => 16 independent gathers in flight
    {
        const int rl = tx >> 3, part = tx & 7;
        int node = row0 + rl;
        if (node >= n) node = n - 1;
        const half8* xr = (const half8*)(xin + (size_t)node * HD);
        half8 xs0 = xr[part * 2 + 0];
        half8 xs1 = xr[part * 2 + 1];
        float acc[2][8];
#pragma unroll
        for (int k = 0; k < 8; ++k) { acc[0][k] = (float)xs0[k]; acc[1][k] = (float)xs1[k]; }

        const int e0 = rp[node], e1 = rp[node + 1];
        for (int eb = e0; eb < e1; eb += 8) {
            int idx = eb + part;
            int c = (idx < e1) ? ci[idx] : node;
#pragma unroll
            for (int j = 0; j < 8; ++j) {
                int cj = __shfl(c, j, 8);
                const half8* xc = (const half8*)(xin + (size_t)cj * HD);
                half8 v0 = xc[part * 2 + 0];
                half8 v1 = xc[part * 2 + 1];
#pragma unroll
                for (int k = 0; k < 8; ++k) {
                    acc[0][k] += (float)v0[k];
                    acc[1][k] += (float)v1[k];
                }
            }
        }
        int deg = e1 - e0;
        if (deg) {
            float fx = (float)(((deg + 7) & ~7) - deg);
#pragma unroll
            for (int k = 0; k < 8; ++k) {
                acc[0][k] -= fx * (float)xs0[k];
                acc[1][k] -= fx * (float)xs1[k];
            }
        }
#pragma unroll
        for (int q = 0; q < 2; ++q) {
            short8 h8s, l8s;
#pragma unroll
            for (int k = 0; k < 8; ++k) { short h, l; split_bf(acc[q][k], h, l); h8s[k] = h; l8s[k] = l; }
            int off = rl * SYB + part * 16 + q * 8;
            *(short8*)&sAh[off] = h8s;
            *(short8*)&sAl[off] = l8s;
        }
    }

    mlp_body(sAh, sAl, xout, w1h, w1l, w2h, w2l, b1, b2, row0, n, wv, lane, quad, lrow);
}

// ------------------------------------------------------------------ pool ----
// batch is sorted; each graph block binary-searches its node range.
__global__ void k_pool(const _Float16* __restrict__ x, const int* __restrict__ batch,
                       float* __restrict__ out, int n)
{
    int g = blockIdx.x, t = threadIdx.x;
    int lo = 0, hi = n;
    while (lo < hi) { int m = (lo + hi) >> 1; if (batch[m] < g) lo = m + 1; else hi = m; }
    int s = lo;
    hi = n;
    while (lo < hi) { int m = (lo + hi) >> 1; if (batch[m] < g + 1) lo = m + 1; else hi = m; }
    int e = lo;
    float sum = 0.f;
    for (int i = s; i < e; ++i) sum += (float)x[(size_t)i * HD + t];
    int cnt = e - s;
    out[(size_t)g * HD + t] = (cnt > 0) ? sum / (float)cnt : 0.f;
}

// ---------------------------------------------------------------- launch ----
extern "C" void kernel_launch(void* const* d_in, const int* in_sizes, int n_in,
                              void* d_out, int out_size, void* d_ws, size_t ws_size,
                              hipStream_t stream)
{
    const int*   tok   = (const int*)d_in[0];
    const int*   eidx  = (const int*)d_in[1];
    const int*   batch = (const int*)d_in[2];
    const float* emb   = (const float*)d_in[3];
    const float* W1    = (const float*)d_in[4];
    const float* b1    = (const float*)d_in[5];
    const float* W2    = (const float*)d_in[6];
    const float* b2    = (const float*)d_in[7];
    float* out = (float*)d_out;

    const int n      = in_sizes[0];
    const int e      = in_sizes[1] / 2;
    const int ngraph = out_size / HD;
    const int L      = in_sizes[4] / (HD * HD);
    const int* src = eidx;
    const int* dst = eidx + e;

    char* w = (char*)d_ws;
    size_t off = 0;
    auto alloc = [&](size_t bytes) -> void* {
        void* p = w + off;
        off = (off + bytes + 255) & ~(size_t)255;
        return p;
    };
    _Float16* xa = (_Float16*)alloc((size_t)(n + TM) * HD * 2);
    _Float16* xb = (_Float16*)alloc((size_t)(n + TM) * HD * 2);
    int* rp    = (int*)alloc((size_t)(n + 1) * 4);
    // zero-init group: deg, fillc contiguous -> ONE memset
    size_t zoff = off;
    int* deg   = (int*)alloc((size_t)n * 4);
    int* fillc = (int*)alloc((size_t)n * 4);
    size_t zbytes = off - zoff;
    int* ci    = (int*)alloc((size_t)e * 4);
    int* bsum  = (int*)alloc(512);
    short* wh  = (short*)alloc((size_t)L * 2 * 16384 * 2);
    short* wl  = (short*)alloc((size_t)L * 2 * 16384 * 2);

    hipMemsetAsync(deg, 0, zbytes, stream);

    int wtot = L * 2 * 16384;
    k_wsplit<<<(wtot + 255) / 256, 256, 0, stream>>>(W1, W2, wh, wl, wtot);

    k_degree<<<(e + 255) / 256, 256, 0, stream>>>(dst, deg, e);
    int nb = (n + 1023) / 1024;
    k_scan1<<<nb, 1024, 0, stream>>>(deg, rp, bsum, n);
    k_scan2<<<1, 128, 0, stream>>>(bsum, nb);
    k_scan3<<<nb, 1024, 0, stream>>>(rp, bsum, n, e);
    k_fill<<<(e + 255) / 256, 256, 0, stream>>>(src, dst, rp, fillc, ci, e);

    const int ngrid = (n + TM - 1) / TM;

    // layer 0: embed fused (emb fp32, L1-hot; per-edge traffic = 4 B token)
    k_gin0<<<ngrid, 256, 0, stream>>>(
        tok, emb, xb, rp, ci,
        wh, wl, wh + 16384, wl + 16384,
        b1, b2, n);

    _Float16* xin = xb;
    _Float16* xo  = xa;
    for (int l = 1; l < L; ++l) {
        const short* lw = wh + (size_t)l * 2 * 16384;
        const short* ll = wl + (size_t)l * 2 * 16384;
        k_gin<<<ngrid, 256, 0, stream>>>(
            xin, xo, rp, ci,
            lw, ll, lw + 16384, ll + 16384,
            b1 + (size_t)l * HD, b2 + (size_t)l * HD, n);
        _Float16* t = xin; xin = xo; xo = t;
    }

    k_pool<<<ngraph, HD, 0, stream>>>(xin, batch, out, n);
}

// Round 17
// 438.742 us; speedup vs baseline: 1.0170x; 1.0170x over previous
//
#include <hip/hip_runtime.h>

#define HD  128   // hidden dim
#define TM  32    // node rows per block in the GIN layer kernel
#define SYB 136   // bf16 LDS stride

typedef __attribute__((ext_vector_type(8))) short    short8;
typedef __attribute__((ext_vector_type(8))) _Float16 half8;
typedef __attribute__((ext_vector_type(4))) float    float4v;

// split fp32 -> bf16 hi + bf16 lo (RNE both), v == hi + lo to ~2^-17 rel
__device__ __forceinline__ void split_bf(float v, short& hi, short& lo) {
    unsigned bv = __float_as_uint(v);
    unsigned hb = (bv + 0x7FFFu + ((bv >> 16) & 1u)) & 0xFFFF0000u;
    hi = (short)(hb >> 16);
    float r = v - __uint_as_float(hb);
    unsigned rv = __float_as_uint(r);
    lo = (short)((rv + 0x7FFFu + ((rv >> 16) & 1u)) >> 16);
}

// ---------------------------------------------------------------- embed ----
__global__ void k_embed(const int* __restrict__ tok, const float* __restrict__ emb,
                        _Float16* __restrict__ x, int n)
{
    int g = blockIdx.x * 256 + threadIdx.x;      // thread = (node, part<16), 8 elems
    if (g < n * 16) {
        int node = g >> 4, part = g & 15;
        const float4* e4 = (const float4*)emb + ((size_t)tok[node] << 5) + part * 2;
        float4 a = e4[0], b = e4[1];
        half8 h;
        h[0] = (_Float16)a.x; h[1] = (_Float16)a.y; h[2] = (_Float16)a.z; h[3] = (_Float16)a.w;
        h[4] = (_Float16)b.x; h[5] = (_Float16)b.y; h[6] = (_Float16)b.z; h[7] = (_Float16)b.w;
        ((half8*)x)[g] = h;
    }
}

// ------------------------------------------------------------- CSR build ----
__global__ void k_degree(const int* __restrict__ dst, int* __restrict__ deg, int e)
{
    int i = blockIdx.x * 256 + threadIdx.x;
    if (i < e) atomicAdd(&deg[dst[i]], 1);
}

__global__ void k_scan1(const int* __restrict__ deg, int* __restrict__ rp,
                        int* __restrict__ bsum, int n)
{
    __shared__ int s[1024];
    int t = threadIdx.x;
    int i = blockIdx.x * 1024 + t;
    int v = (i < n) ? deg[i] : 0;
    s[t] = v; __syncthreads();
    for (int off = 1; off < 1024; off <<= 1) {
        int tmp = (t >= off) ? s[t - off] : 0;
        __syncthreads();
        s[t] += tmp;
        __syncthreads();
    }
    if (i < n) rp[i] = s[t] - v;
    if (t == 1023) bsum[blockIdx.x] = s[1023];
}

__global__ void k_scan2(int* __restrict__ bsum, int nb)
{
    __shared__ int s[128];
    int t = threadIdx.x;
    int v = (t < nb) ? bsum[t] : 0;
    s[t] = v; __syncthreads();
    for (int off = 1; off < 128; off <<= 1) {
        int tmp = (t >= off) ? s[t - off] : 0;
        __syncthreads();
        s[t] += tmp;
        __syncthreads();
    }
    if (t < nb) bsum[t] = s[t] - v;
}

__global__ void k_scan3(int* __restrict__ rp, const int* __restrict__ bsum, int n, int e)
{
    int i = blockIdx.x * 1024 + threadIdx.x;
    if (i < n) rp[i] += bsum[blockIdx.x];
    if (i == 0) rp[n] = e;
}

__global__ void k_fill(const int* __restrict__ src, const int* __restrict__ dst,
                       const int* __restrict__ rp, int* __restrict__ fill,
                       int* __restrict__ ci, int e)
{
    int i = blockIdx.x * 256 + threadIdx.x;
    if (i < e) {
        int d = dst[i];
        int p = atomicAdd(&fill[d], 1);
        ci[rp[d] + p] = src[i];
    }
}

// --------------------------------------------- weight split into B-frags ----
// frag idx f = ((ct*4 + kb)*64 + lane)*8 + j holds
// W[kb*32 + (lane>>4)*8 + j][ct*16 + (lane&15)]  (B-operand of 16x16x32)
__global__ void k_wsplit(const float* __restrict__ W1, const float* __restrict__ W2,
                         short* __restrict__ wh, short* __restrict__ wl, int total)
{
    int g = blockIdx.x * 256 + threadIdx.x;
    if (g >= total) return;
    int f  = g & 16383;
    int m  = (g >> 14) & 1;
    int l  = g >> 15;
    int j    = f & 7;
    int lane = (f >> 3) & 63;
    int kb   = (f >> 9) & 3;
    int ct   = f >> 11;
    int k  = kb * 32 + (lane >> 4) * 8 + j;
    int nn = ct * 16 + (lane & 15);
    const float* W = m ? W2 : W1;
    float v = W[(size_t)l * 16384 + k * 128 + nn];
    short h, lo; split_bf(v, h, lo);
    wh[g] = h; wl[g] = lo;
}

// ------------------------------------------------------- fused GIN layer ----
__global__ __launch_bounds__(256, 4)
void k_gin(const _Float16* __restrict__ xin, _Float16* __restrict__ xout,
           const int* __restrict__ rp, const int* __restrict__ ci,
           const short* __restrict__ w1h, const short* __restrict__ w1l,
           const short* __restrict__ w2h, const short* __restrict__ w2l,
           const float* __restrict__ b1, const float* __restrict__ b2,
           int n)
{
    __shared__ short sAh[TM * SYB];   // Y tile, then H tile (hi)
    __shared__ short sAl[TM * SYB];   // (lo)

    const int tx   = threadIdx.x;
    const int row0 = blockIdx.x * TM;
    const int wv   = tx >> 6, lane = tx & 63;
    const int quad = lane >> 4, lrow = lane & 15;

    // ---- aggregation: Y[row] = x[row] + sum_{j} x[j]
    // 8 lanes/row; shfl-broadcast 8-edge chunks => 16 independent gathers in flight
    {
        const int rl = tx >> 3, part = tx & 7;
        int node = row0 + rl;
        if (node >= n) node = n - 1;             // clamped rows compute garbage, never stored
        const half8* xr = (const half8*)(xin + (size_t)node * HD);
        half8 xs0 = xr[part * 2 + 0];
        half8 xs1 = xr[part * 2 + 1];
        float acc[2][8];
#pragma unroll
        for (int k = 0; k < 8; ++k) { acc[0][k] = (float)xs0[k]; acc[1][k] = (float)xs1[k]; }

        const int e0 = rp[node], e1 = rp[node + 1];
        for (int eb = e0; eb < e1; eb += 8) {
            int idx = eb + part;
            int c = (idx < e1) ? ci[idx] : node;  // ragged tail: substitute self, subtract later
#pragma unroll
            for (int j = 0; j < 8; ++j) {
                int cj = __shfl(c, j, 8);
                const half8* xc = (const half8*)(xin + (size_t)cj * HD);
                half8 v0 = xc[part * 2 + 0];
                half8 v1 = xc[part * 2 + 1];
#pragma unroll
                for (int k = 0; k < 8; ++k) {
                    acc[0][k] += (float)v0[k];
                    acc[1][k] += (float)v1[k];
                }
            }
        }
        int deg = e1 - e0;
        if (deg) {
            float fx = (float)(((deg + 7) & ~7) - deg);   // self-substitutions to remove
#pragma unroll
            for (int k = 0; k < 8; ++k) {
                acc[0][k] -= fx * (float)xs0[k];
                acc[1][k] -= fx * (float)xs1[k];
            }
        }
        // split fp32 -> bf16 hi/lo into LDS (elems part*16 + q*8 + j)
#pragma unroll
        for (int q = 0; q < 2; ++q) {
            short8 h8s, l8s;
#pragma unroll
            for (int k = 0; k < 8; ++k) { short h, l; split_bf(acc[q][k], h, l); h8s[k] = h; l8s[k] = l; }
            int off = rl * SYB + part * 16 + q * 8;
            *(short8*)&sAh[off] = h8s;
            *(short8*)&sAl[off] = l8s;
        }
    }

    // B1 hi frags + bias (issued after gather; latency overlaps barrier + LDS reads)
    short8 Bh[2][4];
    {
        const short8* h8 = (const short8*)w1h;
#pragma unroll
        for (int c = 0; c < 2; ++c)
#pragma unroll
            for (int kb = 0; kb < 4; ++kb)
                Bh[c][kb] = h8[((2 * wv + c) * 4 + kb) * 64 + lane];
    }
    float bb0 = b1[(2 * wv + 0) * 16 + lrow];
    float bb1 = b1[(2 * wv + 1) * 16 + lrow];
    __syncthreads();

    // ---- GEMM1: H = relu(Y @ W1 + b1); rows 0..31, wave cols [32wv, 32wv+32)
    float4v acc1[2][2];
#pragma unroll
    for (int rt = 0; rt < 2; ++rt) {
        acc1[rt][0] = (float4v){bb0, bb0, bb0, bb0};
        acc1[rt][1] = (float4v){bb1, bb1, bb1, bb1};
    }
    {
        const short8* l8 = (const short8*)w1l;
#pragma unroll
        for (int kb = 0; kb < 4; ++kb) {
            short8 Ah[2], Al[2];
#pragma unroll
            for (int rt = 0; rt < 2; ++rt) {
                int off = (rt * 16 + lrow) * SYB + kb * 32 + quad * 8;
                Ah[rt] = *(const short8*)&sAh[off];
                Al[rt] = *(const short8*)&sAl[off];
            }
            short8 Bl0 = l8[((2 * wv + 0) * 4 + kb) * 64 + lane];
            short8 Bl1 = l8[((2 * wv + 1) * 4 + kb) * 64 + lane];
#pragma unroll
            for (int rt = 0; rt < 2; ++rt) {
                acc1[rt][0] = __builtin_amdgcn_mfma_f32_16x16x32_bf16(Ah[rt], Bh[0][kb], acc1[rt][0], 0, 0, 0);
                acc1[rt][0] = __builtin_amdgcn_mfma_f32_16x16x32_bf16(Al[rt], Bh[0][kb], acc1[rt][0], 0, 0, 0);
                acc1[rt][0] = __builtin_amdgcn_mfma_f32_16x16x32_bf16(Ah[rt], Bl0,       acc1[rt][0], 0, 0, 0);
                acc1[rt][1] = __builtin_amdgcn_mfma_f32_16x16x32_bf16(Ah[rt], Bh[1][kb], acc1[rt][1], 0, 0, 0);
                acc1[rt][1] = __builtin_amdgcn_mfma_f32_16x16x32_bf16(Al[rt], Bh[1][kb], acc1[rt][1], 0, 0, 0);
                acc1[rt][1] = __builtin_amdgcn_mfma_f32_16x16x32_bf16(Ah[rt], Bl1,       acc1[rt][1], 0, 0, 0);
            }
        }
    }

    // B2 hi frags + bias (issue before barrier, overlap it)
    short8 Bh2[2][4];
    {
        const short8* h8 = (const short8*)w2h;
#pragma unroll
        for (int c = 0; c < 2; ++c)
#pragma unroll
            for (int kb = 0; kb < 4; ++kb)
                Bh2[c][kb] = h8[((2 * wv + c) * 4 + kb) * 64 + lane];
    }
    float cb0 = b2[(2 * wv + 0) * 16 + lrow];
    float cb1 = b2[(2 * wv + 1) * 16 + lrow];

    __syncthreads();   // all waves done reading Y from LDS

    // H (relu) -> split into sAh/sAl (overwrite Y)
#pragma unroll
    for (int rt = 0; rt < 2; ++rt)
#pragma unroll
        for (int c = 0; c < 2; ++c) {
            int col = (2 * wv + c) * 16 + lrow;
#pragma unroll
            for (int r = 0; r < 4; ++r) {
                int row = rt * 16 + quad * 4 + r;
                float v = fmaxf(acc1[rt][c][r], 0.f);
                short h, l; split_bf(v, h, l);
                sAh[row * SYB + col] = h;
                sAl[row * SYB + col] = l;
            }
        }
    __syncthreads();

    // ---- GEMM2: X' = relu(H @ W2 + b2)
    float4v acc2[2][2];
#pragma unroll
    for (int rt = 0; rt < 2; ++rt) {
        acc2[rt][0] = (float4v){cb0, cb0, cb0, cb0};
        acc2[rt][1] = (float4v){cb1, cb1, cb1, cb1};
    }
    {
        const short8* l8 = (const short8*)w2l;
#pragma unroll
        for (int kb = 0; kb < 4; ++kb) {
            short8 Ah[2], Al[2];
#pragma unroll
            for (int rt = 0; rt < 2; ++rt) {
                int off = (rt * 16 + lrow) * SYB + kb * 32 + quad * 8;
                Ah[rt] = *(const short8*)&sAh[off];
                Al[rt] = *(const short8*)&sAl[off];
            }
            short8 Bl0 = l8[((2 * wv + 0) * 4 + kb) * 64 + lane];
            short8 Bl1 = l8[((2 * wv + 1) * 4 + kb) * 64 + lane];
#pragma unroll
            for (int rt = 0; rt < 2; ++rt) {
                acc2[rt][0] = __builtin_amdgcn_mfma_f32_16x16x32_bf16(Ah[rt], Bh2[0][kb], acc2[rt][0], 0, 0, 0);
                acc2[rt][0] = __builtin_amdgcn_mfma_f32_16x16x32_bf16(Al[rt], Bh2[0][kb], acc2[rt][0], 0, 0, 0);
                acc2[rt][0] = __builtin_amdgcn_mfma_f32_16x16x32_bf16(Ah[rt], Bl0,        acc2[rt][0], 0, 0, 0);
                acc2[rt][1] = __builtin_amdgcn_mfma_f32_16x16x32_bf16(Ah[rt], Bh2[1][kb], acc2[rt][1], 0, 0, 0);
                acc2[rt][1] = __builtin_amdgcn_mfma_f32_16x16x32_bf16(Al[rt], Bh2[1][kb], acc2[rt][1], 0, 0, 0);
                acc2[rt][1] = __builtin_amdgcn_mfma_f32_16x16x32_bf16(Ah[rt], Bl1,        acc2[rt][1], 0, 0, 0);
            }
        }
    }

    // epilogue: relu + store fp16
#pragma unroll
    for (int rt = 0; rt < 2; ++rt)
#pragma unroll
        for (int c = 0; c < 2; ++c) {
            int col = (2 * wv + c) * 16 + lrow;
#pragma unroll
            for (int r = 0; r < 4; ++r) {
                int node = row0 + rt * 16 + quad * 4 + r;
                if (node < n)
                    xout[(size_t)node * HD + col] = (_Float16)fmaxf(acc2[rt][c][r], 0.f);
            }
        }
}

// ------------------------------------------------------------------ pool ----
// batch is sorted; each graph block binary-searches its node range.
__global__ void k_pool(const _Float16* __restrict__ x, const int* __restrict__ batch,
                       float* __restrict__ out, int n)
{
    int g = blockIdx.x, t = threadIdx.x;
    int lo = 0, hi = n;
    while (lo < hi) { int m = (lo + hi) >> 1; if (batch[m] < g) lo = m + 1; else hi = m; }
    int s = lo;
    hi = n;
    while (lo < hi) { int m = (lo + hi) >> 1; if (batch[m] < g + 1) lo = m + 1; else hi = m; }
    int e = lo;
    float sum = 0.f;
    for (int i = s; i < e; ++i) sum += (float)x[(size_t)i * HD + t];
    int cnt = e - s;
    out[(size_t)g * HD + t] = (cnt > 0) ? sum / (float)cnt : 0.f;
}

// ---------------------------------------------------------------- launch ----
extern "C" void kernel_launch(void* const* d_in, const int* in_sizes, int n_in,
                              void* d_out, int out_size, void* d_ws, size_t ws_size,
                              hipStream_t stream)
{
    const int*   tok   = (const int*)d_in[0];
    const int*   eidx  = (const int*)d_in[1];
    const int*   batch = (const int*)d_in[2];
    const float* emb   = (const float*)d_in[3];
    const float* W1    = (const float*)d_in[4];
    const float* b1    = (const float*)d_in[5];
    const float* W2    = (const float*)d_in[6];
    const float* b2    = (const float*)d_in[7];
    float* out = (float*)d_out;

    const int n      = in_sizes[0];
    const int e      = in_sizes[1] / 2;
    const int ngraph = out_size / HD;
    const int L      = in_sizes[4] / (HD * HD);
    const int* src = eidx;
    const int* dst = eidx + e;

    char* w = (char*)d_ws;
    size_t off = 0;
    auto alloc = [&](size_t bytes) -> void* {
        void* p = w + off;
        off = (off + bytes + 255) & ~(size_t)255;
        return p;
    };
    _Float16* xa = (_Float16*)alloc((size_t)(n + TM) * HD * 2);
    _Float16* xb = (_Float16*)alloc((size_t)(n + TM) * HD * 2);
    int* rp    = (int*)alloc((size_t)(n + 1) * 4);
    // zero-init group: deg, fillc contiguous -> ONE memset
    size_t zoff = off;
    int* deg   = (int*)alloc((size_t)n * 4);
    int* fillc = (int*)alloc((size_t)n * 4);
    size_t zbytes = off - zoff;
    int* ci    = (int*)alloc((size_t)e * 4);
    int* bsum  = (int*)alloc(512);
    short* wh  = (short*)alloc((size_t)L * 2 * 16384 * 2);
    short* wl  = (short*)alloc((size_t)L * 2 * 16384 * 2);

    hipMemsetAsync(deg, 0, zbytes, stream);

    k_embed<<<(n * 16 + 255) / 256, 256, 0, stream>>>(tok, emb, xa, n);

    int wtot = L * 2 * 16384;
    k_wsplit<<<(wtot + 255) / 256, 256, 0, stream>>>(W1, W2, wh, wl, wtot);

    k_degree<<<(e + 255) / 256, 256, 0, stream>>>(dst, deg, e);
    int nb = (n + 1023) / 1024;
    k_scan1<<<nb, 1024, 0, stream>>>(deg, rp, bsum, n);
    k_scan2<<<1, 128, 0, stream>>>(bsum, nb);
    k_scan3<<<nb, 1024, 0, stream>>>(rp, bsum, n, e);
    k_fill<<<(e + 255) / 256, 256, 0, stream>>>(src, dst, rp, fillc, ci, e);

    _Float16* xin = xa;
    _Float16* xo  = xb;
    for (int l = 0; l < L; ++l) {
        const short* lw = wh + (size_t)l * 2 * 16384;
        const short* ll = wl + (size_t)l * 2 * 16384;
        k_gin<<<(n + TM - 1) / TM, 256, 0, stream>>>(
            xin, xo, rp, ci,
            lw, ll, lw + 16384, ll + 16384,
            b1 + (size_t)l * HD, b2 + (size_t)l * HD, n);
        _Float16* t = xin; xin = xo; xo = t;
    }

    k_pool<<<ngraph, HD, 0, stream>>>(xin, batch, out, n);
}